// Round 9
// baseline (226.401 us; speedup 1.0000x reference)
//
#include <hip/hip_runtime.h>

using u16 = unsigned short;
typedef __attribute__((ext_vector_type(8))) short short8;
typedef __attribute__((ext_vector_type(4))) float floatx4;

#define NQ 1024
#define NK 2048
#define DD 512

__device__ __forceinline__ u16 f2bf(float f) {
  union { float f; unsigned u; } x; x.f = f;
  unsigned r = (x.u + 0x7fffu + ((x.u >> 16) & 1u)) >> 16;
  return (u16)r;
}
__device__ __forceinline__ float bf2f(u16 u) {
  union { unsigned u; float f; } x; x.u = ((unsigned)u) << 16; return x.f;
}
__device__ __forceinline__ float wave_sum(float v) {
#pragma unroll
  for (int off = 32; off > 0; off >>= 1) v += __shfl_down(v, off, 64);
  return v;
}
__device__ __forceinline__ void gload16(const u16* g, const u16* l) {
  __builtin_amdgcn_global_load_lds(
      (const __attribute__((address_space(1))) void*)g,
      (__attribute__((address_space(3))) void*)l, 16, 0, 0);
}

// ------- fused: LN(inputs) + LN(context) + 3x weight cvt + zero Z/colV ------
__global__ __launch_bounds__(256) void ln_prep(
    const float* __restrict__ X1, const float* __restrict__ G1,
    const float* __restrict__ B1, u16* __restrict__ Y1,
    const float* __restrict__ X2, const float* __restrict__ G2,
    const float* __restrict__ B2, u16* __restrict__ Y2,
    const float* __restrict__ Wq, const float* __restrict__ Wk,
    const float* __restrict__ Wv, u16* __restrict__ wqb,
    u16* __restrict__ wkb, u16* __restrict__ wvb, float* __restrict__ Zero) {
  int row = blockIdx.x;
  const int t = threadIdx.x;
  if (row >= 24576) {
    int bx = row - 24576;
    if (bx < 768) {
      const float* src = bx < 256 ? Wq : (bx < 512 ? Wk : Wv);
      u16* dst = bx < 256 ? wqb : (bx < 512 ? wkb : wvb);
      int i = ((bx & 255) * 256 + t) * 4;
      float4 v = *(const float4*)(src + i);
      ushort4 o;
      o.x = f2bf(v.x); o.y = f2bf(v.y); o.z = f2bf(v.z); o.w = f2bf(v.w);
      *(ushort4*)(dst + i) = o;
    } else {
      int i = ((bx - 768) * 256 + t) * 4;
      float4 z = {0.f, 0.f, 0.f, 0.f};
      *(float4*)(Zero + i) = z;
    }
    return;
  }
  const float *X, *G, *Bv; u16* Y;
  if (row < 8192) { X = X1; G = G1; Bv = B1; Y = Y1; }
  else { row -= 8192; X = X2; G = G2; Bv = B2; Y = Y2; }
  const float2 v = ((const float2*)(X + (long)row * DD))[t];
  float s = v.x + v.y, ss = v.x * v.x + v.y * v.y;
  __shared__ float red[8];
  float a = wave_sum(s), b = wave_sum(ss);
  if ((t & 63) == 0) { red[t >> 6] = a; red[4 + (t >> 6)] = b; }
  __syncthreads();
  float tot = red[0] + red[1] + red[2] + red[3];
  float tss = red[4] + red[5] + red[6] + red[7];
  float mu = tot * (1.f / DD);
  float var = tss * (1.f / DD) - mu * mu;
  float rs = rsqrtf(var + 1e-5f);
  float2 g2 = ((const float2*)G)[t];
  float2 b2 = ((const float2*)Bv)[t];
  ushort2 o;
  o.x = f2bf((v.x - mu) * rs * g2.x + b2.x);
  o.y = f2bf((v.y - mu) * rs * g2.y + b2.y);
  ((ushort2*)(Y + (long)row * DD))[t] = o;
}

// ---------- q-proj + k-proj (B^T GEMM, K=512, BK=64, swizzled LDS) ----------
__global__ __launch_bounds__(256) void gemm_proj(
    const u16* __restrict__ A1, const u16* __restrict__ W1,
    const float* __restrict__ b1, u16* __restrict__ C1,
    const u16* __restrict__ A2, const u16* __restrict__ W2,
    const float* __restrict__ b2, u16* __restrict__ C2) {
  __shared__ u16 lA[128 * 64];
  __shared__ u16 lB[128 * 64];
  const u16 *A, *B; const float* bias; u16* Cout;
  int m0 = blockIdx.x * 128;
  if (blockIdx.x < 64) { A = A1; B = W1; bias = b1; Cout = C1; }
  else { A = A2; B = W2; bias = b2; Cout = C2; m0 = (blockIdx.x - 64) * 128; }
  const int n0 = blockIdx.y * 128;
  const int t = threadIdx.x, wave = t >> 6, lane = t & 63;
  const int fm = lane & 15, fq = lane >> 4;
  const int wm = (wave >> 1) * 64, wn = (wave & 1) * 64;

  const int srow = t >> 3;
  const int swz = ((t & 7) ^ (srow & 7)) * 8;
  const u16* gA = A + (long)(m0 + srow) * 512 + swz;
  const u16* gB = B + (long)(n0 + srow) * 512 + swz;
  u16* dA = lA + wave * 512;
  u16* dB = lB + wave * 512;

  floatx4 acc[4][4];
#pragma unroll
  for (int x = 0; x < 4; ++x)
#pragma unroll
    for (int y = 0; y < 4; ++y) { floatx4 z = {0.f, 0.f, 0.f, 0.f}; acc[x][y] = z; }

#pragma unroll 1
  for (int kt = 0; kt < 8; ++kt) {
    gload16(gA, dA);
    gload16(gA + 32L * 512, dA + 2048);
    gload16(gA + 64L * 512, dA + 4096);
    gload16(gA + 96L * 512, dA + 6144);
    gload16(gB, dB);
    gload16(gB + 32L * 512, dB + 2048);
    gload16(gB + 64L * 512, dB + 4096);
    gload16(gB + 96L * 512, dB + 6144);
    gA += 64; gB += 64;
    __syncthreads();
#pragma unroll
    for (int ks = 0; ks < 2; ++ks) {
      short8 af[4], bfr[4];
      const int csl = ((ks * 4 + fq) ^ (fm & 7)) * 8;
#pragma unroll
      for (int x = 0; x < 4; ++x)
        af[x] = *(const short8*)&lA[(wm + x * 16 + fm) * 64 + csl];
#pragma unroll
      for (int y = 0; y < 4; ++y)
        bfr[y] = *(const short8*)&lB[(wn + y * 16 + fm) * 64 + csl];
#pragma unroll
      for (int x = 0; x < 4; ++x)
#pragma unroll
        for (int y = 0; y < 4; ++y)
          acc[x][y] = __builtin_amdgcn_mfma_f32_16x16x32_bf16(af[x], bfr[y], acc[x][y], 0, 0, 0);
    }
    __syncthreads();
  }

  float bs[4];
#pragma unroll
  for (int y = 0; y < 4; ++y) bs[y] = bias[n0 + wn + y * 16 + fm];
#pragma unroll
  for (int x = 0; x < 4; ++x)
#pragma unroll
    for (int y = 0; y < 4; ++y)
#pragma unroll
      for (int r = 0; r < 4; ++r) {
        int row = m0 + wm + x * 16 + fq * 4 + r;
        int col = n0 + wn + y * 16 + fm;
        Cout[(long)row * 512 + col] = f2bf(acc[x][y][r] + bs[y]);
      }
}

// ------- merged: QK (blocks 0..1023) + v-projT unscaled (1024..1535) --------
// QK: b=x&7 (XCD), nt=(x>>3)&15, mt=x>>7. E=exp(val*scale); Z colsum atomics.
// vproj: e=x-1024: mt=e&3 (Wv rows), nt=e>>2 (cb rows, 128 tiles).
//        vT[b][d][j] = val+bv[d] (UNSCALED); colV[b][d] += row sums.
__global__ __launch_bounds__(256) void qk_vproj(
    const u16* __restrict__ qb, const u16* __restrict__ kb,
    u16* __restrict__ E, float* __restrict__ Z,
    const u16* __restrict__ wvb, const u16* __restrict__ cb,
    const float* __restrict__ bv, u16* __restrict__ vT,
    float* __restrict__ colV, float scale) {
  __shared__ u16 lA[128 * 64];
  __shared__ u16 lB[128 * 64];
  __shared__ float colred[128];

  const int bx = blockIdx.x;
  const bool is_qk = bx < 1024;
  const u16 *A, *B;
  int m0, n0, b;
  if (is_qk) {
    b = bx & 7;
    n0 = ((bx >> 3) & 15) * 128;
    m0 = (bx >> 7) * 128;
    A = qb + (long)b * (1024L * 512);
    B = kb + (long)b * (2048L * 512);
  } else {
    int e = bx - 1024;
    m0 = (e & 3) * 128;
    n0 = (e >> 2) * 128;
    b = 0;
    A = wvb;
    B = cb;
  }
  const int t = threadIdx.x, wave = t >> 6, lane = t & 63;
  const int fm = lane & 15, fq = lane >> 4;
  const int wm = (wave >> 1) * 64, wn = (wave & 1) * 64;

  const int srow = t >> 3;
  const int swz = ((t & 7) ^ (srow & 7)) * 8;
  const u16* gA = A + (long)(m0 + srow) * 512 + swz;
  const u16* gB = B + (long)(n0 + srow) * 512 + swz;
  u16* dA = lA + wave * 512;
  u16* dB = lB + wave * 512;

  floatx4 acc[4][4];
#pragma unroll
  for (int x = 0; x < 4; ++x)
#pragma unroll
    for (int y = 0; y < 4; ++y) { floatx4 z = {0.f, 0.f, 0.f, 0.f}; acc[x][y] = z; }

#pragma unroll 1
  for (int kt = 0; kt < 8; ++kt) {
    gload16(gA, dA);
    gload16(gA + 32L * 512, dA + 2048);
    gload16(gA + 64L * 512, dA + 4096);
    gload16(gA + 96L * 512, dA + 6144);
    gload16(gB, dB);
    gload16(gB + 32L * 512, dB + 2048);
    gload16(gB + 64L * 512, dB + 4096);
    gload16(gB + 96L * 512, dB + 6144);
    gA += 64; gB += 64;
    __syncthreads();
#pragma unroll
    for (int ks = 0; ks < 2; ++ks) {
      short8 af[4], bfr[4];
      const int csl = ((ks * 4 + fq) ^ (fm & 7)) * 8;
#pragma unroll
      for (int x = 0; x < 4; ++x)
        af[x] = *(const short8*)&lA[(wm + x * 16 + fm) * 64 + csl];
#pragma unroll
      for (int y = 0; y < 4; ++y)
        bfr[y] = *(const short8*)&lB[(wn + y * 16 + fm) * 64 + csl];
#pragma unroll
      for (int x = 0; x < 4; ++x)
#pragma unroll
        for (int y = 0; y < 4; ++y)
          acc[x][y] = __builtin_amdgcn_mfma_f32_16x16x32_bf16(af[x], bfr[y], acc[x][y], 0, 0, 0);
    }
    __syncthreads();
  }

  if (is_qk) {
    float s4[4] = {0.f, 0.f, 0.f, 0.f};
    u16* Eg = E + (long)b * (1024L * 2048);
#pragma unroll
    for (int x = 0; x < 4; ++x)
#pragma unroll
      for (int y = 0; y < 4; ++y)
#pragma unroll
        for (int r = 0; r < 4; ++r) {
          int row = m0 + wm + x * 16 + fq * 4 + r;
          int col = n0 + wn + y * 16 + fm;
          float e = __expf(acc[x][y][r] * scale);
          s4[y] += e;
          Eg[(long)row * 2048 + col] = f2bf(e);
        }
#pragma unroll
    for (int y = 0; y < 4; ++y) {
      s4[y] += __shfl_xor(s4[y], 16, 64);
      s4[y] += __shfl_xor(s4[y], 32, 64);
    }
    if (t < 128) colred[t] = 0.f;
    __syncthreads();
    if (fq == 0) {
#pragma unroll
      for (int y = 0; y < 4; ++y) atomicAdd(&colred[wn + y * 16 + fm], s4[y]);
    }
    __syncthreads();
    if (t < 128) atomicAdd(&Z[b * 2048 + n0 + t], colred[t]);
  } else {
    const int bb = n0 >> 11;
    const int j0c = n0 & 2047;
    float bsr[4][4];
#pragma unroll
    for (int x = 0; x < 4; ++x)
#pragma unroll
      for (int r = 0; r < 4; ++r)
        bsr[x][r] = bv[m0 + wm + x * 16 + fq * 4 + r];
    u16* Cg = vT + (long)bb * (512L * 2048) + j0c;
    float rs[4][4];
#pragma unroll
    for (int x = 0; x < 4; ++x)
#pragma unroll
      for (int r = 0; r < 4; ++r) rs[x][r] = 0.f;
#pragma unroll
    for (int x = 0; x < 4; ++x)
#pragma unroll
      for (int y = 0; y < 4; ++y)
#pragma unroll
        for (int r = 0; r < 4; ++r) {
          int rowd = m0 + wm + x * 16 + fq * 4 + r;
          int col = wn + y * 16 + fm;
          float val = acc[x][y][r] + bsr[x][r];
          rs[x][r] += val;
          Cg[(long)rowd * 2048 + col] = f2bf(val);
        }
#pragma unroll
    for (int x = 0; x < 4; ++x)
#pragma unroll
      for (int r = 0; r < 4; ++r) {
        float s = rs[x][r];
        s += __shfl_xor(s, 1, 64);
        s += __shfl_xor(s, 2, 64);
        s += __shfl_xor(s, 4, 64);
        s += __shfl_xor(s, 8, 64);
        if (fm == 0)
          atomicAdd(&colV[bb * 512 + m0 + wm + x * 16 + fq * 4 + r], s);
      }
  }
}

// ------------- scaleV: vT[b][d][j] *= rcp(Z[b][j]), short8/thread -----------
__global__ __launch_bounds__(256) void scaleV(u16* __restrict__ vT,
                                              const float* __restrict__ Z) {
  const long f = ((long)blockIdx.x * 256 + threadIdx.x) * 8;
  const int b = (int)(f >> 20);
  const int j = (int)(f & 2047);
  const float* zp = Z + b * 2048 + j;
  short8 v = *(const short8*)(vT + f);
  short8 o;
#pragma unroll
  for (int k = 0; k < 8; ++k)
    o[k] = (short)f2bf(bf2f((u16)v[k]) * __builtin_amdgcn_rcpf(zp[k]));
  *(short8*)(vT + f) = o;
}

// ------- PV: out[b][i][d] = (sum_j E[i,j]*vT[d,j] + eps*colV[d]) * invR[i] --
// 64x64 tile, BK=64. 1D grid, id%8 = b for XCD batch-affinity (E[b] in L2).
// R[i] inline via extra MFMA with invZ (bf16) B-fragment.
__global__ __launch_bounds__(256) void gemm_pv(const u16* __restrict__ E,
    const u16* __restrict__ V, const float* __restrict__ colV,
    const float* __restrict__ Z, float* __restrict__ out) {
  __shared__ u16 lA[64 * 64];
  __shared__ u16 lB[64 * 64];
  __shared__ u16 sZb[2048];
  const int id = blockIdx.x;
  const int b = id & 7;
  const int m0 = ((id >> 3) & 15) * 64, n0 = (id >> 7) * 64;
  const int t = threadIdx.x, wave = t >> 6, lane = t & 63;
  const int fm = lane & 15, fq = lane >> 4;
  const int wm = (wave >> 1) * 32, wn = (wave & 1) * 32;

  {
    int i = t * 8;
    float4 z0 = *(const float4*)(Z + b * 2048 + i);
    float4 z1 = *(const float4*)(Z + b * 2048 + i + 4);
    short8 o;
    o[0] = (short)f2bf(__builtin_amdgcn_rcpf(z0.x));
    o[1] = (short)f2bf(__builtin_amdgcn_rcpf(z0.y));
    o[2] = (short)f2bf(__builtin_amdgcn_rcpf(z0.z));
    o[3] = (short)f2bf(__builtin_amdgcn_rcpf(z0.w));
    o[4] = (short)f2bf(__builtin_amdgcn_rcpf(z1.x));
    o[5] = (short)f2bf(__builtin_amdgcn_rcpf(z1.y));
    o[6] = (short)f2bf(__builtin_amdgcn_rcpf(z1.z));
    o[7] = (short)f2bf(__builtin_amdgcn_rcpf(z1.w));
    *(short8*)&sZb[i] = o;
  }

  const int srow = t >> 3;
  const int swz = ((t & 7) ^ (srow & 7)) * 8;
  const u16* gA = E + (long)b * (1024L * 2048) + (long)(m0 + srow) * 2048 + swz;
  const u16* gB = V + (long)b * (512L * 2048) + (long)(n0 + srow) * 2048 + swz;
  u16* dA = lA + wave * 512;
  u16* dB = lB + wave * 512;

  floatx4 acc[2][2];
  floatx4 accR[2];
#pragma unroll
  for (int x = 0; x < 2; ++x) {
    floatx4 z = {0.f, 0.f, 0.f, 0.f};
    accR[x] = z;
#pragma unroll
    for (int y = 0; y < 2; ++y) acc[x][y] = z;
  }

#pragma unroll 1
  for (int kt = 0; kt < 32; ++kt) {
    gload16(gA, dA);
    gload16(gA + 32L * 2048, dA + 2048);
    gload16(gB, dB);
    gload16(gB + 32L * 2048, dB + 2048);
    gA += 64; gB += 64;
    __syncthreads();
#pragma unroll
    for (int ks = 0; ks < 2; ++ks) {
      short8 af[2], bfr[2];
      const int chunk = ks * 4 + fq;
      const int csl = (chunk ^ (fm & 7)) * 8;
#pragma unroll
      for (int x = 0; x < 2; ++x)
        af[x] = *(const short8*)&lA[(wm + x * 16 + fm) * 64 + csl];
#pragma unroll
      for (int y = 0; y < 2; ++y)
        bfr[y] = *(const short8*)&lB[(wn + y * 16 + fm) * 64 + csl];
      short8 zf = *(const short8*)&sZb[kt * 64 + chunk * 8];
#pragma unroll
      for (int x = 0; x < 2; ++x) {
#pragma unroll
        for (int y = 0; y < 2; ++y)
          acc[x][y] = __builtin_amdgcn_mfma_f32_16x16x32_bf16(af[x], bfr[y], acc[x][y], 0, 0, 0);
        accR[x] = __builtin_amdgcn_mfma_f32_16x16x32_bf16(af[x], zf, accR[x], 0, 0, 0);
      }
    }
    __syncthreads();
  }

  float cv[2];
#pragma unroll
  for (int y = 0; y < 2; ++y) cv[y] = colV[b * 512 + n0 + wn + y * 16 + fm];
  float* og = out + (long)b * (1024L * 512);
#pragma unroll
  for (int x = 0; x < 2; ++x)
#pragma unroll
    for (int r = 0; r < 4; ++r) {
      float invR = __builtin_amdgcn_rcpf(accR[x][r] + 2048.f * 1e-8f);
      int row = m0 + wm + x * 16 + fq * 4 + r;
#pragma unroll
      for (int y = 0; y < 2; ++y) {
        int col = n0 + wn + y * 16 + fm;
        og[(long)row * 512 + col] = (acc[x][y][r] + 1e-8f * cv[y]) * invR;
      }
    }
}

extern "C" void kernel_launch(void* const* d_in, const int* in_sizes, int n_in,
                              void* d_out, int out_size, void* d_ws, size_t ws_size,
                              hipStream_t stream) {
  const float* inputs  = (const float*)d_in[0];
  const float* context = (const float*)d_in[1];
  const float* ln_in_g = (const float*)d_in[2];
  const float* ln_in_b = (const float*)d_in[3];
  const float* ln_ctx_g = (const float*)d_in[4];
  const float* ln_ctx_b = (const float*)d_in[5];
  const float* Wq = (const float*)d_in[6];
  const float* bq = (const float*)d_in[7];
  const float* Wk = (const float*)d_in[8];
  const float* bk = (const float*)d_in[9];
  const float* Wv = (const float*)d_in[10];
  const float* bv = (const float*)d_in[11];
  float* out = (float*)d_out;

  u16* ws = (u16*)d_ws;
  u16* xb  = ws;                        // [8192][512]
  u16* qb  = xb + 8192L * 512;          // [8192][512]
  u16* cb  = qb + 8192L * 512;          // [16384][512]
  u16* wqb = cb + 16384L * 512;         // [512][512]
  u16* wkb = wqb + 512L * 512;
  u16* wvb = wkb + 512L * 512;
  u16* kb  = wvb + 512L * 512;          // [16384][512]
  u16* vTs = kb + 16384L * 512;         // [8][512][2048]
  u16* E   = vTs + 8L * 512 * 2048;     // [8][1024][2048]
  float* Z    = (float*)(E + 8L * 1024 * 2048);   // [8][2048] raw col sums
  float* colV = Z + 8L * 2048;                    // [8][512]

  const float scale = 0.04419417382415922f;  // 512^-0.5

  // 1: LN(inputs)+LN(context) + weight cvt + zero Z/colV
  ln_prep<<<25364, 256, 0, stream>>>(inputs, ln_in_g, ln_in_b, xb,
                                     context, ln_ctx_g, ln_ctx_b, cb,
                                     Wq, Wk, Wv, wqb, wkb, wvb, Z);
  // 2: q-proj (bx<64) + k-proj (bx>=64)
  gemm_proj<<<dim3(192, 4, 1), 256, 0, stream>>>(xb, wqb, bq, qb,
                                                 cb, wkb, bk, kb);
  // 3: merged QK (E, Z) + v-projT unscaled (vT, colV)
  qk_vproj<<<1536, 256, 0, stream>>>(qb, kb, E, Z, wvb, cb, bv, vTs,
                                     colV, scale);
  // 4: vT *= rcp(Z)
  scaleV<<<4096, 256, 0, stream>>>(vTs, Z);
  // 5: PV with inline R, XCD batch-affinity
  gemm_pv<<<1024, 256, 0, stream>>>(E, vTs, colV, Z, out);
}

// Round 10
// 207.382 us; speedup vs baseline: 1.0917x; 1.0917x over previous
//
#include <hip/hip_runtime.h>

using u16 = unsigned short;
typedef __attribute__((ext_vector_type(8))) short short8;
typedef __attribute__((ext_vector_type(4))) float floatx4;

#define NQ 1024
#define NK 2048
#define DD 512

__device__ __forceinline__ u16 f2bf(float f) {
  union { float f; unsigned u; } x; x.f = f;
  unsigned r = (x.u + 0x7fffu + ((x.u >> 16) & 1u)) >> 16;
  return (u16)r;
}
__device__ __forceinline__ float bf2f(u16 u) {
  union { unsigned u; float f; } x; x.u = ((unsigned)u) << 16; return x.f;
}
__device__ __forceinline__ float wave_sum(float v) {
#pragma unroll
  for (int off = 32; off > 0; off >>= 1) v += __shfl_down(v, off, 64);
  return v;
}
__device__ __forceinline__ void gload16(const u16* g, const u16* l) {
  __builtin_amdgcn_global_load_lds(
      (const __attribute__((address_space(1))) void*)g,
      (__attribute__((address_space(3))) void*)l, 16, 0, 0);
}

// ---- fused: wave-per-row LN (inputs+context) + weight cvt + zero Z/colV ----
__global__ __launch_bounds__(256) void ln_prep(
    const float* __restrict__ X1, const float* __restrict__ G1,
    const float* __restrict__ B1, u16* __restrict__ Y1,
    const float* __restrict__ X2, const float* __restrict__ G2,
    const float* __restrict__ B2, u16* __restrict__ Y2,
    const float* __restrict__ Wq, const float* __restrict__ Wk,
    const float* __restrict__ Wv, u16* __restrict__ wqb,
    u16* __restrict__ wkb, u16* __restrict__ wvb, float* __restrict__ Zero) {
  const int bx = blockIdx.x;
  const int t = threadIdx.x;
  if (bx >= 6144) {
    int e = bx - 6144;
    if (e < 768) {
      const float* src = e < 256 ? Wq : (e < 512 ? Wk : Wv);
      u16* dst = e < 256 ? wqb : (e < 512 ? wkb : wvb);
      int i = ((e & 255) * 256 + t) * 4;
      float4 v = *(const float4*)(src + i);
      ushort4 o;
      o.x = f2bf(v.x); o.y = f2bf(v.y); o.z = f2bf(v.z); o.w = f2bf(v.w);
      *(ushort4*)(dst + i) = o;
    } else {
      int i = ((e - 768) * 256 + t) * 4;
      float4 z = {0.f, 0.f, 0.f, 0.f};
      *(float4*)(Zero + i) = z;
    }
    return;
  }
  const int wave = t >> 6, lane = t & 63;
  int row = bx * 4 + wave;
  const float *X, *G, *Bv; u16* Y;
  if (row < 8192) { X = X1; G = G1; Bv = B1; Y = Y1; }
  else { row -= 8192; X = X2; G = G2; Bv = B2; Y = Y2; }
  const float4* Xp = (const float4*)(X + (long)row * DD);
  float4 v0 = Xp[lane * 2], v1 = Xp[lane * 2 + 1];
  float s = v0.x + v0.y + v0.z + v0.w + v1.x + v1.y + v1.z + v1.w;
  float ss = v0.x * v0.x + v0.y * v0.y + v0.z * v0.z + v0.w * v0.w +
             v1.x * v1.x + v1.y * v1.y + v1.z * v1.z + v1.w * v1.w;
  s = wave_sum(s);  s = __shfl(s, 0, 64);
  ss = wave_sum(ss); ss = __shfl(ss, 0, 64);
  float mu = s * (1.f / DD);
  float var = ss * (1.f / DD) - mu * mu;
  float rs = rsqrtf(var + 1e-5f);
  const float4* Gp = (const float4*)G;
  const float4* Bp = (const float4*)Bv;
  float4 g0 = Gp[lane * 2], g1 = Gp[lane * 2 + 1];
  float4 b0 = Bp[lane * 2], b1 = Bp[lane * 2 + 1];
  short8 o;
  o[0] = (short)f2bf((v0.x - mu) * rs * g0.x + b0.x);
  o[1] = (short)f2bf((v0.y - mu) * rs * g0.y + b0.y);
  o[2] = (short)f2bf((v0.z - mu) * rs * g0.z + b0.z);
  o[3] = (short)f2bf((v0.w - mu) * rs * g0.w + b0.w);
  o[4] = (short)f2bf((v1.x - mu) * rs * g1.x + b1.x);
  o[5] = (short)f2bf((v1.y - mu) * rs * g1.y + b1.y);
  o[6] = (short)f2bf((v1.z - mu) * rs * g1.z + b1.z);
  o[7] = (short)f2bf((v1.w - mu) * rs * g1.w + b1.w);
  *(short8*)(Y + (long)row * DD + lane * 8) = o;
}

// ---------- q-proj + k-proj (B^T GEMM, K=512, BK=64, swizzled LDS) ----------
// Epilogue stages the 128x128 bf16 C-tile in the K-loop LDS (32 KB), then
// 16-lanes-per-row coalesced short8 stores.
__global__ __launch_bounds__(256) void gemm_proj(
    const u16* __restrict__ A1, const u16* __restrict__ W1,
    const float* __restrict__ b1, u16* __restrict__ C1,
    const u16* __restrict__ A2, const u16* __restrict__ W2,
    const float* __restrict__ b2, u16* __restrict__ C2) {
  __shared__ u16 smem[16384];   // lA | lB in K-loop; 128x128 C-tile in epilogue
  u16* lA = smem;
  u16* lB = smem + 8192;
  const u16 *A, *B; const float* bias; u16* Cout;
  int m0 = blockIdx.x * 128;
  if (blockIdx.x < 64) { A = A1; B = W1; bias = b1; Cout = C1; }
  else { A = A2; B = W2; bias = b2; Cout = C2; m0 = (blockIdx.x - 64) * 128; }
  const int n0 = blockIdx.y * 128;
  const int t = threadIdx.x, wave = t >> 6, lane = t & 63;
  const int fm = lane & 15, fq = lane >> 4;
  const int wm = (wave >> 1) * 64, wn = (wave & 1) * 64;

  const int srow = t >> 3;
  const int swz = ((t & 7) ^ (srow & 7)) * 8;
  const u16* gA = A + (long)(m0 + srow) * 512 + swz;
  const u16* gB = B + (long)(n0 + srow) * 512 + swz;
  u16* dA = lA + wave * 512;
  u16* dB = lB + wave * 512;

  floatx4 acc[4][4];
#pragma unroll
  for (int x = 0; x < 4; ++x)
#pragma unroll
    for (int y = 0; y < 4; ++y) { floatx4 z = {0.f, 0.f, 0.f, 0.f}; acc[x][y] = z; }

#pragma unroll 1
  for (int kt = 0; kt < 8; ++kt) {
    gload16(gA, dA);
    gload16(gA + 32L * 512, dA + 2048);
    gload16(gA + 64L * 512, dA + 4096);
    gload16(gA + 96L * 512, dA + 6144);
    gload16(gB, dB);
    gload16(gB + 32L * 512, dB + 2048);
    gload16(gB + 64L * 512, dB + 4096);
    gload16(gB + 96L * 512, dB + 6144);
    gA += 64; gB += 64;
    __syncthreads();
#pragma unroll
    for (int ks = 0; ks < 2; ++ks) {
      short8 af[4], bfr[4];
      const int csl = ((ks * 4 + fq) ^ (fm & 7)) * 8;
#pragma unroll
      for (int x = 0; x < 4; ++x)
        af[x] = *(const short8*)&lA[(wm + x * 16 + fm) * 64 + csl];
#pragma unroll
      for (int y = 0; y < 4; ++y)
        bfr[y] = *(const short8*)&lB[(wn + y * 16 + fm) * 64 + csl];
#pragma unroll
      for (int x = 0; x < 4; ++x)
#pragma unroll
        for (int y = 0; y < 4; ++y)
          acc[x][y] = __builtin_amdgcn_mfma_f32_16x16x32_bf16(af[x], bfr[y], acc[x][y], 0, 0, 0);
    }
    __syncthreads();
  }

  float bs[4];
#pragma unroll
  for (int y = 0; y < 4; ++y) bs[y] = bias[n0 + wn + y * 16 + fm];
#pragma unroll
  for (int x = 0; x < 4; ++x)
#pragma unroll
    for (int y = 0; y < 4; ++y) {
      const int cblk = (wn >> 4) + y;
#pragma unroll
      for (int r = 0; r < 4; ++r) {
        int rowl = wm + x * 16 + fq * 4 + r;
        smem[rowl * 128 + ((cblk ^ fq) * 16) + fm] = f2bf(acc[x][y][r] + bs[y]);
      }
    }
  __syncthreads();
#pragma unroll
  for (int p = 0; p < 8; ++p) {
    int rowl = p * 16 + (t >> 4);
    int c = t & 15;
    int q = (rowl >> 2) & 3;
    short8 v = *(const short8*)&smem[rowl * 128 + (((c >> 1) ^ q) * 16) + (c & 1) * 8];
    *(short8*)(Cout + (long)(m0 + rowl) * 512 + n0 + c * 8) = v;
  }
}

// ------- merged: QK (blocks 0..1023) + v-projT unscaled (1024..1535) --------
// Both epilogues stage the 128x128 bf16 tile through the K-loop LDS.
__global__ __launch_bounds__(256) void qk_vproj(
    const u16* __restrict__ qb, const u16* __restrict__ kb,
    u16* __restrict__ E, float* __restrict__ Z,
    const u16* __restrict__ wvb, const u16* __restrict__ cb,
    const float* __restrict__ bv, u16* __restrict__ vT,
    float* __restrict__ colV, float scale) {
  __shared__ u16 smem[16384];
  __shared__ float colred[128];
  u16* lA = smem;
  u16* lB = smem + 8192;

  const int bx = blockIdx.x;
  const bool is_qk = bx < 1024;
  const u16 *A, *B;
  int m0, n0, b;
  if (is_qk) {
    b = bx & 7;
    n0 = ((bx >> 3) & 15) * 128;
    m0 = (bx >> 7) * 128;
    A = qb + (long)b * (1024L * 512);
    B = kb + (long)b * (2048L * 512);
  } else {
    int e = bx - 1024;
    m0 = (e & 3) * 128;
    n0 = (e >> 2) * 128;
    b = 0;
    A = wvb;
    B = cb;
  }
  const int t = threadIdx.x, wave = t >> 6, lane = t & 63;
  const int fm = lane & 15, fq = lane >> 4;
  const int wm = (wave >> 1) * 64, wn = (wave & 1) * 64;

  const int srow = t >> 3;
  const int swz = ((t & 7) ^ (srow & 7)) * 8;
  const u16* gA = A + (long)(m0 + srow) * 512 + swz;
  const u16* gB = B + (long)(n0 + srow) * 512 + swz;
  u16* dA = lA + wave * 512;
  u16* dB = lB + wave * 512;

  floatx4 acc[4][4];
#pragma unroll
  for (int x = 0; x < 4; ++x)
#pragma unroll
    for (int y = 0; y < 4; ++y) { floatx4 z = {0.f, 0.f, 0.f, 0.f}; acc[x][y] = z; }

#pragma unroll 1
  for (int kt = 0; kt < 8; ++kt) {
    gload16(gA, dA);
    gload16(gA + 32L * 512, dA + 2048);
    gload16(gA + 64L * 512, dA + 4096);
    gload16(gA + 96L * 512, dA + 6144);
    gload16(gB, dB);
    gload16(gB + 32L * 512, dB + 2048);
    gload16(gB + 64L * 512, dB + 4096);
    gload16(gB + 96L * 512, dB + 6144);
    gA += 64; gB += 64;
    __syncthreads();
#pragma unroll
    for (int ks = 0; ks < 2; ++ks) {
      short8 af[4], bfr[4];
      const int csl = ((ks * 4 + fq) ^ (fm & 7)) * 8;
#pragma unroll
      for (int x = 0; x < 4; ++x)
        af[x] = *(const short8*)&lA[(wm + x * 16 + fm) * 64 + csl];
#pragma unroll
      for (int y = 0; y < 4; ++y)
        bfr[y] = *(const short8*)&lB[(wn + y * 16 + fm) * 64 + csl];
#pragma unroll
      for (int x = 0; x < 4; ++x)
#pragma unroll
        for (int y = 0; y < 4; ++y)
          acc[x][y] = __builtin_amdgcn_mfma_f32_16x16x32_bf16(af[x], bfr[y], acc[x][y], 0, 0, 0);
    }
    __syncthreads();
  }

  if (is_qk) {
    float s4[4] = {0.f, 0.f, 0.f, 0.f};
#pragma unroll
    for (int x = 0; x < 4; ++x)
#pragma unroll
      for (int y = 0; y < 4; ++y) {
        const int cblk = (wn >> 4) + y;
#pragma unroll
        for (int r = 0; r < 4; ++r) {
          int rowl = wm + x * 16 + fq * 4 + r;
          float e = __expf(acc[x][y][r] * scale);
          s4[y] += e;
          smem[rowl * 128 + ((cblk ^ fq) * 16) + fm] = f2bf(e);
        }
      }
#pragma unroll
    for (int y = 0; y < 4; ++y) {
      s4[y] += __shfl_xor(s4[y], 16, 64);
      s4[y] += __shfl_xor(s4[y], 32, 64);
    }
    if (t < 128) colred[t] = 0.f;
    __syncthreads();
    u16* Eg = E + (long)b * (1024L * 2048);
#pragma unroll
    for (int p = 0; p < 8; ++p) {
      int rowl = p * 16 + (t >> 4);
      int c = t & 15;
      int q = (rowl >> 2) & 3;
      short8 v = *(const short8*)&smem[rowl * 128 + (((c >> 1) ^ q) * 16) + (c & 1) * 8];
      *(short8*)(Eg + (long)(m0 + rowl) * 2048 + n0 + c * 8) = v;
    }
    if (fq == 0) {
#pragma unroll
      for (int y = 0; y < 4; ++y) atomicAdd(&colred[wn + y * 16 + fm], s4[y]);
    }
    __syncthreads();
    if (t < 128) atomicAdd(&Z[b * 2048 + n0 + t], colred[t]);
  } else {
    const int bb = n0 >> 11;
    const int j0c = n0 & 2047;
    float bsr[4][4];
#pragma unroll
    for (int x = 0; x < 4; ++x)
#pragma unroll
      for (int r = 0; r < 4; ++r)
        bsr[x][r] = bv[m0 + wm + x * 16 + fq * 4 + r];
    float rs[4][4];
#pragma unroll
    for (int x = 0; x < 4; ++x)
#pragma unroll
      for (int r = 0; r < 4; ++r) rs[x][r] = 0.f;
#pragma unroll
    for (int x = 0; x < 4; ++x)
#pragma unroll
      for (int y = 0; y < 4; ++y) {
        const int cblk = (wn >> 4) + y;
#pragma unroll
        for (int r = 0; r < 4; ++r) {
          int rowl = wm + x * 16 + fq * 4 + r;
          float val = acc[x][y][r] + bsr[x][r];
          rs[x][r] += val;
          smem[rowl * 128 + ((cblk ^ fq) * 16) + fm] = f2bf(val);
        }
      }
    __syncthreads();
    u16* Cg = vT + (long)bb * (512L * 2048) + j0c;
#pragma unroll
    for (int p = 0; p < 8; ++p) {
      int rowl = p * 16 + (t >> 4);
      int c = t & 15;
      int q = (rowl >> 2) & 3;
      short8 v = *(const short8*)&smem[rowl * 128 + (((c >> 1) ^ q) * 16) + (c & 1) * 8];
      *(short8*)(Cg + (long)(m0 + rowl) * 2048 + c * 8) = v;
    }
#pragma unroll
    for (int x = 0; x < 4; ++x)
#pragma unroll
      for (int r = 0; r < 4; ++r) {
        float s = rs[x][r];
        s += __shfl_xor(s, 1, 64);
        s += __shfl_xor(s, 2, 64);
        s += __shfl_xor(s, 4, 64);
        s += __shfl_xor(s, 8, 64);
        if (fm == 0)
          atomicAdd(&colV[bb * 512 + m0 + wm + x * 16 + fq * 4 + r], s);
      }
  }
}

// ------------- scaleV: vT[b][d][j] *= rcp(Z[b][j]), short8/thread -----------
__global__ __launch_bounds__(256) void scaleV(u16* __restrict__ vT,
                                              const float* __restrict__ Z) {
  const long f = ((long)blockIdx.x * 256 + threadIdx.x) * 8;
  const int b = (int)(f >> 20);
  const float* zp = Z + b * 2048 + (int)(f & 2047);
  short8 v = *(const short8*)(vT + f);
  short8 o;
#pragma unroll
  for (int k = 0; k < 8; ++k)
    o[k] = (short)f2bf(bf2f((u16)v[k]) * __builtin_amdgcn_rcpf(zp[k]));
  *(short8*)(vT + f) = o;
}

// ------- PV: out[b][i][d] = (sum_j E[i,j]*vT[d,j] + eps*colV[d]) * invR[i] --
// 64x64 tile, BK=64, 1D grid id%8=b (XCD). R inline via MFMA with invZ frag.
// fp32 64x64 C-tile staged through the 16 KB K-loop LDS, float4 stores.
__global__ __launch_bounds__(256) void gemm_pv(const u16* __restrict__ E,
    const u16* __restrict__ V, const float* __restrict__ colV,
    const float* __restrict__ Z, float* __restrict__ out) {
  __shared__ u16 smem[8192];     // lA | lB in K-loop; 64x64 fp32 tile after
  __shared__ u16 sZb[2048];
  u16* lA = smem;
  u16* lB = smem + 4096;
  const int id = blockIdx.x;
  const int b = id & 7;
  const int m0 = ((id >> 3) & 15) * 64, n0 = (id >> 7) * 64;
  const int t = threadIdx.x, wave = t >> 6, lane = t & 63;
  const int fm = lane & 15, fq = lane >> 4;
  const int wm = (wave >> 1) * 32, wn = (wave & 1) * 32;

  {
    int i = t * 8;
    float4 z0 = *(const float4*)(Z + b * 2048 + i);
    float4 z1 = *(const float4*)(Z + b * 2048 + i + 4);
    short8 o;
    o[0] = (short)f2bf(__builtin_amdgcn_rcpf(z0.x));
    o[1] = (short)f2bf(__builtin_amdgcn_rcpf(z0.y));
    o[2] = (short)f2bf(__builtin_amdgcn_rcpf(z0.z));
    o[3] = (short)f2bf(__builtin_amdgcn_rcpf(z0.w));
    o[4] = (short)f2bf(__builtin_amdgcn_rcpf(z1.x));
    o[5] = (short)f2bf(__builtin_amdgcn_rcpf(z1.y));
    o[6] = (short)f2bf(__builtin_amdgcn_rcpf(z1.z));
    o[7] = (short)f2bf(__builtin_amdgcn_rcpf(z1.w));
    *(short8*)&sZb[i] = o;
  }

  const int srow = t >> 3;
  const int swz = ((t & 7) ^ (srow & 7)) * 8;
  const u16* gA = E + (long)b * (1024L * 2048) + (long)(m0 + srow) * 2048 + swz;
  const u16* gB = V + (long)b * (512L * 2048) + (long)(n0 + srow) * 2048 + swz;
  u16* dA = lA + wave * 512;
  u16* dB = lB + wave * 512;

  floatx4 acc[2][2];
  floatx4 accR[2];
#pragma unroll
  for (int x = 0; x < 2; ++x) {
    floatx4 z = {0.f, 0.f, 0.f, 0.f};
    accR[x] = z;
#pragma unroll
    for (int y = 0; y < 2; ++y) acc[x][y] = z;
  }

#pragma unroll 1
  for (int kt = 0; kt < 32; ++kt) {
    gload16(gA, dA);
    gload16(gA + 32L * 2048, dA + 2048);
    gload16(gB, dB);
    gload16(gB + 32L * 2048, dB + 2048);
    gA += 64; gB += 64;
    __syncthreads();
#pragma unroll
    for (int ks = 0; ks < 2; ++ks) {
      short8 af[2], bfr[2];
      const int chunk = ks * 4 + fq;
      const int csl = (chunk ^ (fm & 7)) * 8;
#pragma unroll
      for (int x = 0; x < 2; ++x)
        af[x] = *(const short8*)&lA[(wm + x * 16 + fm) * 64 + csl];
#pragma unroll
      for (int y = 0; y < 2; ++y)
        bfr[y] = *(const short8*)&lB[(wn + y * 16 + fm) * 64 + csl];
      short8 zf = *(const short8*)&sZb[kt * 64 + chunk * 8];
#pragma unroll
      for (int x = 0; x < 2; ++x) {
#pragma unroll
        for (int y = 0; y < 2; ++y)
          acc[x][y] = __builtin_amdgcn_mfma_f32_16x16x32_bf16(af[x], bfr[y], acc[x][y], 0, 0, 0);
        accR[x] = __builtin_amdgcn_mfma_f32_16x16x32_bf16(af[x], zf, accR[x], 0, 0, 0);
      }
    }
    __syncthreads();
  }

  float cv[2];
#pragma unroll
  for (int y = 0; y < 2; ++y) cv[y] = colV[b * 512 + n0 + wn + y * 16 + fm];
  float* sO = (float*)smem;
#pragma unroll
  for (int x = 0; x < 2; ++x)
#pragma unroll
    for (int r = 0; r < 4; ++r) {
      float invR = __builtin_amdgcn_rcpf(accR[x][r] + 2048.f * 1e-8f);
      int rowl = wm + x * 16 + fq * 4 + r;
#pragma unroll
      for (int y = 0; y < 2; ++y) {
        const int cblk = (wn >> 4) + y;
        sO[rowl * 64 + ((cblk ^ fq) * 16) + fm] =
            (acc[x][y][r] + 1e-8f * cv[y]) * invR;
      }
    }
  __syncthreads();
  float* og = out + (long)b * (1024L * 512);
#pragma unroll
  for (int p = 0; p < 4; ++p) {
    int rowl = p * 16 + (t >> 4);
    int c = t & 15;
    int q = (rowl >> 2) & 3;
    float4 v = *(const float4*)&sO[rowl * 64 + (((c >> 2) ^ q) * 16) + (c & 3) * 4];
    *(float4*)(og + (long)(m0 + rowl) * 512 + n0 + c * 4) = v;
  }
}

extern "C" void kernel_launch(void* const* d_in, const int* in_sizes, int n_in,
                              void* d_out, int out_size, void* d_ws, size_t ws_size,
                              hipStream_t stream) {
  const float* inputs  = (const float*)d_in[0];
  const float* context = (const float*)d_in[1];
  const float* ln_in_g = (const float*)d_in[2];
  const float* ln_in_b = (const float*)d_in[3];
  const float* ln_ctx_g = (const float*)d_in[4];
  const float* ln_ctx_b = (const float*)d_in[5];
  const float* Wq = (const float*)d_in[6];
  const float* bq = (const float*)d_in[7];
  const float* Wk = (const float*)d_in[8];
  const float* bk = (const float*)d_in[9];
  const float* Wv = (const float*)d_in[10];
  const float* bv = (const float*)d_in[11];
  float* out = (float*)d_out;

  u16* ws = (u16*)d_ws;
  u16* xb  = ws;                        // [8192][512]
  u16* qb  = xb + 8192L * 512;          // [8192][512]
  u16* cb  = qb + 8192L * 512;          // [16384][512]
  u16* wqb = cb + 16384L * 512;         // [512][512]
  u16* wkb = wqb + 512L * 512;
  u16* wvb = wkb + 512L * 512;
  u16* kb  = wvb + 512L * 512;          // [16384][512]
  u16* vTs = kb + 16384L * 512;         // [8][512][2048]
  u16* E   = vTs + 8L * 512 * 2048;     // [8][1024][2048]
  float* Z    = (float*)(E + 8L * 1024 * 2048);   // [8][2048] raw col sums
  float* colV = Z + 8L * 2048;                    // [8][512]

  const float scale = 0.04419417382415922f;  // 512^-0.5

  // 1: LN(inputs)+LN(context) wave-per-row + weight cvt + zero Z/colV
  ln_prep<<<6932, 256, 0, stream>>>(inputs, ln_in_g, ln_in_b, xb,
                                    context, ln_ctx_g, ln_ctx_b, cb,
                                    Wq, Wk, Wv, wqb, wkb, wvb, Z);
  // 2: q-proj (bx<64) + k-proj (bx>=64)
  gemm_proj<<<dim3(192, 4, 1), 256, 0, stream>>>(xb, wqb, bq, qb,
                                                 cb, wkb, bk, kb);
  // 3: merged QK (E, Z) + v-projT unscaled (vT, colV)
  qk_vproj<<<1536, 256, 0, stream>>>(qb, kb, E, Z, wvb, cb, bv, vTs,
                                     colV, scale);
  // 4: vT *= rcp(Z)
  scaleV<<<4096, 256, 0, stream>>>(vTs, Z);
  // 5: PV with inline R, XCD batch-affinity, staged fp32 epilogue
  gemm_pv<<<1024, 256, 0, stream>>>(E, vTs, colV, Z, out);
}